// Round 1
// baseline (441.020 us; speedup 1.0000x reference)
//
#include <hip/hip_runtime.h>
#include <math.h>

#define BN 64
#define PN 8732
#define CN 81
#define GN 32

// ws layout (bytes):
//   0   : float acc[3]  {sl1_sum, ce_pos_sum, hardneg_sum}
//   64  : int n_pos[BN]
//   512 : int idx_per_gt[BN*GN]
//   8704: int cls[BN*PN]
//   2244096: float ce_neg[BN*PN]
#define ACC_OFF   0
#define NPOS_OFF  64
#define IDXG_OFF  512
#define CLS_OFF   8704
#define CEN_OFF   2244096

// ---------------- Pass A: idx_per_gt[b,g] = argmax_p IoU(gt, prior) (first occurrence)
__global__ __launch_bounds__(256) void pass_a(const float* __restrict__ boxes,
                                              const float* __restrict__ prior,
                                              int* __restrict__ idx_per_gt) {
    int b = blockIdx.x / GN, g = blockIdx.x % GN;
    const float* gb = boxes + (size_t)(b * GN + g) * 4;
    float gx0 = gb[0], gy0 = gb[1], gx1 = gb[2], gy1 = gb[3];
    float ga = (gx1 - gx0) * (gy1 - gy0);
    float best = -1.0f; int bi = PN;
    for (int p = threadIdx.x; p < PN; p += 256) {
        const float* pc = prior + (size_t)p * 4;
        float cx = pc[0], cy = pc[1], w = pc[2], h = pc[3];
        float px0 = cx - w * 0.5f, py0 = cy - h * 0.5f;
        float px1 = cx + w * 0.5f, py1 = cy + h * 0.5f;
        float pa = (px1 - px0) * (py1 - py0);
        float ix = fminf(gx1, px1) - fmaxf(gx0, px0); ix = fmaxf(ix, 0.0f);
        float iy = fminf(gy1, py1) - fmaxf(gy0, py0); iy = fmaxf(iy, 0.0f);
        float inter = ix * iy;
        float iou = inter / (ga + pa - inter);
        if (iou > best) { best = iou; bi = p; }   // strict > keeps first occurrence
    }
    // wave butterfly: bigger val wins, tie -> smaller idx
    for (int o = 1; o < 64; o <<= 1) {
        float ov = __shfl_xor(best, o);
        int   oi = __shfl_xor(bi, o);
        if (ov > best || (ov == best && oi < bi)) { best = ov; bi = oi; }
    }
    __shared__ float sv[4]; __shared__ int si[4];
    int wid = threadIdx.x >> 6;
    if ((threadIdx.x & 63) == 0) { sv[wid] = best; si[wid] = bi; }
    __syncthreads();
    if (threadIdx.x == 0) {
        for (int w = 1; w < 4; w++)
            if (sv[w] > best || (sv[w] == best && si[w] < bi)) { best = sv[w]; bi = si[w]; }
        idx_per_gt[b * GN + g] = bi;
    }
}

// ---------------- Pass B: per-prior match, labels, smooth-L1 on positives
__global__ __launch_bounds__(256) void pass_b(const float* __restrict__ pred_boxes,
                                              const float* __restrict__ boxes,
                                              const int* __restrict__ labels,
                                              const float* __restrict__ prior,
                                              const int* __restrict__ idx_per_gt,
                                              int* __restrict__ cls,
                                              float* __restrict__ acc,
                                              int* __restrict__ n_pos) {
    int b = blockIdx.y;
    __shared__ float bx[GN][4];
    __shared__ int lb[GN];
    __shared__ int ig[GN];
    int t = threadIdx.x;
    if (t < GN) {
        const float* src = boxes + (size_t)(b * GN + t) * 4;
        bx[t][0] = src[0]; bx[t][1] = src[1]; bx[t][2] = src[2]; bx[t][3] = src[3];
        lb[t] = labels[b * GN + t];
        ig[t] = idx_per_gt[b * GN + t];
    }
    __syncthreads();
    int p = blockIdx.x * 256 + t;
    float sl1 = 0.0f; int posc = 0;
    if (p < PN) {
        const float* pc = prior + (size_t)p * 4;
        float cx = pc[0], cy = pc[1], w = pc[2], h = pc[3];
        float px0 = cx - w * 0.5f, py0 = cy - h * 0.5f;
        float px1 = cx + w * 0.5f, py1 = cy + h * 0.5f;
        float pa = (px1 - px0) * (py1 - py0);
        float best = -1.0f; int bi = 0;
        for (int g = 0; g < GN; g++) {
            float gx0 = bx[g][0], gy0 = bx[g][1], gx1 = bx[g][2], gy1 = bx[g][3];
            float ga = (gx1 - gx0) * (gy1 - gy0);
            float ix = fminf(gx1, px1) - fmaxf(gx0, px0); ix = fmaxf(ix, 0.0f);
            float iy = fminf(gy1, py1) - fmaxf(gy0, py0); iy = fmaxf(iy, 0.0f);
            float inter = ix * iy;
            float iou = inter / (ga + pa - inter);
            if (iou > best) { best = iou; bi = g; }   // first occurrence along G
        }
        // scatter override: numpy last-g-wins
        for (int g = 0; g < GN; g++) if (ig[g] == p) { bi = g; best = 1.0f; }
        int lab = (best < 0.5f) ? 0 : lb[bi];
        cls[(size_t)b * PN + p] = lab;
        if (lab != 0) {
            posc = 1;
            float gx0 = bx[bi][0], gy0 = bx[bi][1], gx1 = bx[bi][2], gy1 = bx[bi][3];
            float gcx = (gx0 + gx1) * 0.5f, gcy = (gy0 + gy1) * 0.5f;
            float gw = gx1 - gx0, gh = gy1 - gy0;
            float tb0 = (gcx - cx) / (w / 10.0f);
            float tb1 = (gcy - cy) / (h / 10.0f);
            float tb2 = logf(gw / w) * 5.0f;
            float tb3 = logf(gh / h) * 5.0f;
            const float* pb = pred_boxes + (size_t)(b * PN + p) * 4;
            float tb[4] = {tb0, tb1, tb2, tb3};
            for (int i = 0; i < 4; i++) {
                float d = pb[i] - tb[i];
                float ad = fabsf(d);
                sl1 += (ad < 1.0f) ? 0.5f * d * d : (ad - 0.5f);
            }
        }
    }
    for (int o = 1; o < 64; o <<= 1) {
        sl1  += __shfl_xor(sl1, o);
        posc += __shfl_xor(posc, o);
    }
    if ((t & 63) == 0) {
        if (sl1 != 0.0f) atomicAdd(&acc[0], sl1);
        if (posc)        atomicAdd(&n_pos[b], posc);
    }
}

// ---------------- Pass C: cross entropy per (b,p); writes ce_neg, accumulates pos CE
#define TILE 32
__global__ __launch_bounds__(256) void pass_c(const float* __restrict__ logits,
                                              const int* __restrict__ cls,
                                              float* __restrict__ ce_neg,
                                              float* __restrict__ acc) {
    __shared__ float sm[TILE * CN];   // 2592 floats
    int tile = blockIdx.x;
    size_t base = (size_t)tile * TILE * CN;
    for (int i = threadIdx.x; i < TILE * CN; i += 256) sm[i] = logits[base + i];
    __syncthreads();
    int r = threadIdx.x >> 3, s = threadIdx.x & 7;
    size_t row = (size_t)tile * TILE + r;
    float m = -INFINITY;
    for (int j = s; j < CN; j += 8) m = fmaxf(m, sm[r * CN + j]);
    for (int o = 1; o < 8; o <<= 1) m = fmaxf(m, __shfl_xor(m, o));
    float se = 0.0f;
    for (int j = s; j < CN; j += 8) se += expf(sm[r * CN + j] - m);
    for (int o = 1; o < 8; o <<= 1) se += __shfl_xor(se, o);
    float logZ = m + logf(se);
    float cepos = 0.0f;
    if (s == 0) {
        int lab = cls[row];
        float ce = logZ - sm[r * CN + lab];
        ce_neg[row] = (lab != 0) ? 0.0f : fmaxf(ce, 0.0f);  // clamp keeps bits monotonic
        cepos = (lab != 0) ? ce : 0.0f;
    }
    for (int o = 1; o < 64; o <<= 1) cepos += __shfl_xor(cepos, o);
    if ((threadIdx.x & 63) == 0 && cepos != 0.0f) atomicAdd(&acc[1], cepos);
}

// ---------------- Pass D: per-image top-k(3*n_pos) sum of ce_neg via bitpattern bisection
__global__ __launch_bounds__(1024) void pass_d(const float* __restrict__ ce_neg,
                                               const int* __restrict__ n_pos,
                                               float* __restrict__ acc) {
    __shared__ float data[PN];          // 34928 B
    __shared__ float fred[16];
    __shared__ int   ired[16];
    __shared__ float fbr;
    __shared__ int   ibr;
    int b = blockIdx.x;
    for (int i = threadIdx.x; i < PN; i += 1024) data[i] = ce_neg[(size_t)b * PN + i];
    __syncthreads();
    int k = 3 * n_pos[b];
    if (k > PN) k = PN;
    float result = 0.0f;
    int wid = threadIdx.x >> 6, lane = threadIdx.x & 63;
    if (k > 0) {
        unsigned lo = 0u, hi = 0x7f7fffffu;
        if (k < PN) {
            while (lo < hi) {
                unsigned mid = lo + (hi - lo + 1u) / 2u;
                float mf = __uint_as_float(mid);
                int c = 0;
                for (int i = threadIdx.x; i < PN; i += 1024) c += (data[i] >= mf) ? 1 : 0;
                for (int o = 1; o < 64; o <<= 1) c += __shfl_xor(c, o);
                if (lane == 0) ired[wid] = c;
                __syncthreads();
                if (threadIdx.x == 0) {
                    int tot = 0;
                    for (int w = 0; w < 16; w++) tot += ired[w];
                    ibr = tot;
                }
                __syncthreads();
                int tot = ibr;
                __syncthreads();
                if (tot >= k) lo = mid; else hi = mid - 1u;
            }
        } else {
            lo = 0u;   // take everything: vk=0, sum all positives
        }
        float vk = (k < PN) ? __uint_as_float(lo) : -1.0f;
        float s = 0.0f; int cg = 0;
        for (int i = threadIdx.x; i < PN; i += 1024) {
            float x = data[i];
            if (x > vk) { s += x; cg++; }
        }
        for (int o = 1; o < 64; o <<= 1) { s += __shfl_xor(s, o); cg += __shfl_xor(cg, o); }
        if (lane == 0) { fred[wid] = s; ired[wid] = cg; }
        __syncthreads();
        if (threadIdx.x == 0) {
            float st = 0.0f; int ct = 0;
            for (int w = 0; w < 16; w++) { st += fred[w]; ct += ired[w]; }
            result = (k < PN) ? (st + __uint_as_float(lo) * (float)(k - ct)) : st;
            atomicAdd(&acc[2], result);
        }
    }
}

// ---------------- Pass E: finalize
__global__ void pass_e(const int* __restrict__ n_pos, const float* __restrict__ acc,
                       float* __restrict__ out) {
    if (threadIdx.x == 0) {
        int npt = 0;
        for (int b = 0; b < BN; b++) npt += n_pos[b];
        float n = (float)npt;
        out[0] = (acc[1] + acc[2]) / n + acc[0] / (n * 4.0f);
    }
}

extern "C" void kernel_launch(void* const* d_in, const int* in_sizes, int n_in,
                              void* d_out, int out_size, void* d_ws, size_t ws_size,
                              hipStream_t stream) {
    const float* pred_boxes  = (const float*)d_in[0];
    const float* pred_logits = (const float*)d_in[1];
    const float* boxes       = (const float*)d_in[2];
    const int*   labels      = (const int*)d_in[3];
    const float* prior       = (const float*)d_in[4];
    float* out = (float*)d_out;
    char* ws = (char*)d_ws;

    float* acc    = (float*)(ws + ACC_OFF);
    int*   n_pos  = (int*)(ws + NPOS_OFF);
    int*   idxg   = (int*)(ws + IDXG_OFF);
    int*   cls    = (int*)(ws + CLS_OFF);
    float* ce_neg = (float*)(ws + CEN_OFF);

    hipMemsetAsync(ws, 0, 512, stream);

    pass_a<<<BN * GN, 256, 0, stream>>>(boxes, prior, idxg);

    dim3 gb((PN + 255) / 256, BN);
    pass_b<<<gb, 256, 0, stream>>>(pred_boxes, boxes, labels, prior, idxg, cls, acc, n_pos);

    pass_c<<<(BN * PN) / TILE, 256, 0, stream>>>(pred_logits, cls, ce_neg, acc);

    pass_d<<<BN, 1024, 0, stream>>>(ce_neg, n_pos, acc);

    pass_e<<<1, 64, 0, stream>>>(n_pos, acc, out);
}